// Round 10
// baseline (368.933 us; speedup 1.0000x reference)
//
#include <hip/hip_runtime.h>
#include <cfloat>
#include <cstddef>
#include <cstdint>

#define HW 9216
#define MROWS 2304
#define STRIPS 18
#define GPS 32          // 16-col groups per strip (STRIPW 512)
#define NGRP 576        // 9216/16 total groups
#define EPI_BLOCKS 512

typedef _Float16 half8 __attribute__((ext_vector_type(8)));
typedef float f32x4 __attribute__((ext_vector_type(4)));

// bpack (B fragments, 16x16x32 layout): half8 index = (((dt*8+bb)*2 + c)*576 + g)*64 + lane
// apack (A fragments): half8 index = ((((bb*36+rg)*4 + rt)*2 + c)*2 + dt)*64 + lane
constexpr size_t OFF_BPB  = 0;                         // 18,874,368 B
constexpr size_t OFF_APA  = OFF_BPB + 2ull*8*2*NGRP*64*16;
constexpr size_t OFF_PVAL = OFF_APA + 8ull*36*4*2*2*64*16;     // +4,718,592
constexpr size_t OFF_PIDX = OFF_PVAL + 8ull*STRIPS*MROWS*4;    // 1,327,104 each
constexpr size_t OFF_ORI  = OFF_PIDX + 8ull*STRIPS*MROWS*4;
constexpr size_t OFF_CFO  = OFF_ORI  + 36864;
constexpr size_t OFF_CFF  = OFF_CFO  + 147456;
constexpr size_t OFF_SO   = OFF_CFF  + 147456;
constexpr size_t OFF_SF   = OFF_SO   + 1024;
constexpr size_t OFF_INVA = OFF_SF   + 1024;                   // 8*2304 f32
constexpr size_t OFF_BAR  = OFF_INVA + 73728;                  // 2 ints (grid barrier)

// K0: fused pack. grid (324, 8 bb), 256t.
//  x < 288: B-side pack + zero cf flags.  x >= 288: A-side pack + row inv norms.
//  Block (0,0) also zeroes the epilogue barrier counters.
__global__ __launch_bounds__(256) void pack_kernel(
    const float* __restrict__ x, const float* __restrict__ flip,
    half8* __restrict__ bpB, half8* __restrict__ apA, float* __restrict__ invA,
    int* __restrict__ cfo, int* __restrict__ cff, int* __restrict__ bar)
{
    __shared__ float nsq[8][32];
    __shared__ float ivs[32];
    __shared__ float red[4][64];

    int bb = blockIdx.y, b = bb >> 1, br = bb & 1;
    int t = threadIdx.x;
    if (blockIdx.x == 0 && blockIdx.y == 0 && t < 2) bar[t] = 0;

    if (blockIdx.x < 288) {
        // ---- B-side ----
        int col = t & 31, oct = t >> 5;
        int j = blockIdx.x * 32 + col;
        const float* Bm = br ? (flip + (size_t)b * 64 * HW)
                             : (x + (size_t)b * 128 * HW + (size_t)64 * HW);
        float v[8];
        float part = 0.f;
        #pragma unroll
        for (int e = 0; e < 8; ++e) {
            v[e] = Bm[(size_t)(oct * 8 + e) * HW + j];
            part += v[e] * v[e];
        }
        nsq[oct][col] = part;
        __syncthreads();
        if (oct == 0) {
            float tot = 0.f;
            #pragma unroll
            for (int o = 0; o < 8; ++o) tot += nsq[o][col];
            int r = j / 96, cc = j % 96;
            int cb = br ? 28 : 20;
            bool masked = (r >= 24 && r < 72 && cc >= cb && cc < cb + 48);
            float iv = 1.f / sqrtf(tot);
            ivs[col] = masked ? __builtin_nanf("") : iv;
            if (br == 0) cfo[b * HW + j] = 0; else cff[b * HW + j] = 0;
        }
        __syncthreads();
        float iv = ivs[col];
        half8 hv, lv;
        #pragma unroll
        for (int e = 0; e < 8; ++e) {
            float s = v[e] * iv;
            _Float16 h = (_Float16)s;
            hv[e] = h;
            lv[e] = (_Float16)(s - (float)h);
        }
        int g = j >> 4, n = j & 15, c = oct >> 2, q = oct & 3;
        int lane = n + 16 * q;
        bpB[(((size_t)(0 * 8 + bb) * 2 + c) * NGRP + g) * 64 + lane] = hv;
        bpB[(((size_t)(1 * 8 + bb) * 2 + c) * NGRP + g) * 64 + lane] = lv;
    } else {
        // ---- A-side ----
        int rg = blockIdx.x - 288;
        int ml = t & 63, s = t >> 6;
        int cbase = br ? 28 : 20;
        int m = rg * 64 + ml;
        int pix = (24 + m / 48) * 96 + cbase + (m % 48);
        const float* A = x + (size_t)b * 128 * HW;
        float v[16];
        float part = 0.f;
        #pragma unroll
        for (int e = 0; e < 16; ++e) {
            v[e] = A[(size_t)(s * 16 + e) * HW + pix];
            part += v[e] * v[e];
        }
        red[s][ml] = part;
        __syncthreads();
        if (s == 0) {
            float tot = red[0][ml] + red[1][ml] + red[2][ml] + red[3][ml];
            invA[bb * MROWS + m] = 1.f / sqrtf(tot);
        }
        int rt = ml >> 4;
        size_t fragbase = (((size_t)bb * 36 + rg) * 4 + rt) * 2;
        #pragma unroll
        for (int h = 0; h < 2; ++h) {
            int o = 2 * s + h;
            int c = o >> 2, q = o & 3;
            int lane = (ml & 15) + 16 * q;
            half8 hv, lv;
            #pragma unroll
            for (int e = 0; e < 8; ++e) {
                float a = v[h * 8 + e];
                _Float16 hh = (_Float16)a;
                hv[e] = hh;
                lv[e] = (_Float16)(a - (float)hh);
            }
            apA[((fragbase + c) * 2 + 0) * 64 + lane] = hv;
            apA[((fragbase + c) * 2 + 1) * 64 + lane] = lv;
        }
    }
}

// K1: MFMA masked-argmax, fp16 split-3, 16x16x32_f16. 128t blocks (2 waves),
// wave = one (bb,strip,rg) unit; no LDS, no barriers; double-buffered B prefetch.
// NOTE: reg cap must stay >= ~144 (unified VGPR+AGPR) -> max 3 waves/EU, else spill (R9).
// grid: x = 144 (bb + 8*strip -> XCD pinning on bb), y = 18 (rg pairs).
__global__ __launch_bounds__(128, 3) void argmax_kernel(
    const half8* __restrict__ apA, const half8* __restrict__ bpB,
    float* __restrict__ pval, int* __restrict__ pidx)
{
    int bb = blockIdx.x & 7, strip = blockIdx.x >> 3;
    int wv = threadIdx.x >> 6, lane = threadIdx.x & 63;
    int rg = blockIdx.y * 2 + wv;
    int n = lane & 15;

    // A fragments: ah/al[rt][c]
    half8 ah[4][2], al[4][2];
    {
        size_t base = ((size_t)bb * 36 + rg) * 4;
        #pragma unroll
        for (int rt = 0; rt < 4; ++rt)
            #pragma unroll
            for (int c = 0; c < 2; ++c) {
                ah[rt][c] = apA[(((base + rt) * 2 + c) * 2 + 0) * 64 + lane];
                al[rt][c] = apA[(((base + rt) * 2 + c) * 2 + 1) * 64 + lane];
            }
    }

    float rv[16]; int rix[16];
    #pragma unroll
    for (int r = 0; r < 16; ++r) { rv[r] = -FLT_MAX; rix[r] = 0x7fffffff; }

    const f32x4 ZERO = {};
    int g0 = strip * GPS;

    const half8* pH0 = bpB + (((size_t)(bb) * 2 + 0) * NGRP) * 64 + lane;
    const half8* pH1 = bpB + (((size_t)(bb) * 2 + 1) * NGRP) * 64 + lane;
    const half8* pL0 = bpB + (((size_t)(8 + bb) * 2 + 0) * NGRP) * 64 + lane;
    const half8* pL1 = bpB + (((size_t)(8 + bb) * 2 + 1) * NGRP) * 64 + lane;

    half8 buf0[4], buf1[4];
    auto ldb = [&](half8* d, int g) {
        d[0] = pH0[(size_t)g * 64];
        d[1] = pH1[(size_t)g * 64];
        d[2] = pL0[(size_t)g * 64];
        d[3] = pL1[(size_t)g * 64];
    };
    auto compute = [&](const half8* bf, int gi) {
        f32x4 acc[4];
        #pragma unroll
        for (int rt = 0; rt < 4; ++rt) {
            acc[rt] = __builtin_amdgcn_mfma_f32_16x16x32_f16(ah[rt][0], bf[0], ZERO, 0, 0, 0);
            acc[rt] = __builtin_amdgcn_mfma_f32_16x16x32_f16(al[rt][0], bf[0], acc[rt], 0, 0, 0);
            acc[rt] = __builtin_amdgcn_mfma_f32_16x16x32_f16(ah[rt][0], bf[2], acc[rt], 0, 0, 0);
            acc[rt] = __builtin_amdgcn_mfma_f32_16x16x32_f16(ah[rt][1], bf[1], acc[rt], 0, 0, 0);
            acc[rt] = __builtin_amdgcn_mfma_f32_16x16x32_f16(al[rt][1], bf[1], acc[rt], 0, 0, 0);
            acc[rt] = __builtin_amdgcn_mfma_f32_16x16x32_f16(ah[rt][1], bf[3], acc[rt], 0, 0, 0);
        }
        int j = (g0 + gi) * 16 + n;
        #pragma unroll
        for (int rt = 0; rt < 4; ++rt)
            #pragma unroll
            for (int r = 0; r < 4; ++r) {
                float s = acc[rt][r];
                int slot = rt * 4 + r;
                if (s > rv[slot]) { rv[slot] = s; rix[slot] = j; }
            }
    };

    ldb(buf0, g0);
    #pragma unroll 1
    for (int gi = 0; gi < GPS; gi += 2) {
        ldb(buf1, g0 + gi + 1);
        compute(buf0, gi);
        int gnext = gi + 2 < GPS ? g0 + gi + 2 : g0 + gi + 1;  // clamp (dummy reload)
        ldb(buf0, gnext);
        compute(buf1, gi + 1);
    }

    #pragma unroll
    for (int slot = 0; slot < 16; ++slot) {
        float v = rv[slot]; int ix = rix[slot];
        #pragma unroll
        for (int off = 1; off <= 8; off <<= 1) {
            float ov = __shfl_xor(v, off, 16);
            int   oi = __shfl_xor(ix, off, 16);
            if (ov > v || (ov == v && oi < ix)) { v = ov; ix = oi; }
        }
        if (n == 0) {
            int q = lane >> 4;
            int rt = slot >> 2, r = slot & 3;
            int mm = rg * 64 + rt * 16 + q * 4 + r;
            pval[((size_t)bb * STRIPS + strip) * MROWS + mm] = v;
            pidx[((size_t)bb * STRIPS + strip) * MROWS + mm] = ix;
        }
    }
}

// soft grid barrier: co-resident blocks only (512 blocks x 256t, ~2/CU -- safe)
__device__ __forceinline__ void grid_barrier(int* bar, int nblk) {
    __syncthreads();
    if (threadIdx.x == 0) {
        __threadfence();
        __hip_atomic_fetch_add(bar, 1, __ATOMIC_ACQ_REL, __HIP_MEMORY_SCOPE_AGENT);
        while (__hip_atomic_load(bar, __ATOMIC_ACQUIRE, __HIP_MEMORY_SCOPE_AGENT) < nblk) {}
        __threadfence();
    }
    __syncthreads();
}

// K2: fused epilogue. 512 blocks x 256t.
// Phase 1: merge 18 strips -> ori + col-flag scatter. Phase 2: ssum (one (bb,c)
// pair per block). Phase 3: assemble output. Soft grid barriers between phases.
__global__ __launch_bounds__(256) void epilogue_kernel(
    const float* __restrict__ x, const float* __restrict__ flip,
    const float* __restrict__ pval, const int* __restrict__ pidx,
    const float* __restrict__ invA, int* __restrict__ ori,
    int* __restrict__ cfo, int* __restrict__ cff,
    float* __restrict__ So, float* __restrict__ Sf,
    float* __restrict__ out, int* __restrict__ bar)
{
    int t = threadIdx.x;
    int g = blockIdx.x * 256 + t;

    // ---- Phase 1: merge ----
    if (g < 4 * MROWS) {
        int b = g / MROWS, m = g % MROWS;
        float bv[2]; int bi[2];
        #pragma unroll
        for (int br = 0; br < 2; ++br) {
            int bb = b * 2 + br;
            float v = -FLT_MAX; int id = 0x7fffffff;
            #pragma unroll
            for (int s = 0; s < STRIPS; ++s) {
                float pv = pval[((size_t)bb * STRIPS + s) * MROWS + m];
                int   pi = pidx[((size_t)bb * STRIPS + s) * MROWS + m];
                if (pv > v || (pv == v && pi < id)) { v = pv; id = pi; }
            }
            bv[br] = v * invA[bb * MROWS + m];
            bi[br] = id;
        }
        bool o = bv[0] >= bv[1];
        ori[g] = o ? 1 : 0;
        cfo[b * HW + bi[0]] = 1;
        cff[b * HW + bi[1]] = 1;
    }
    grid_barrier(&bar[0], EPI_BLOCKS);

    // ---- Phase 2: ssum, one (bb,c) pair per block ----
    {
        int pair = blockIdx.x;            // 0..511
        int bb = pair >> 6, c = pair & 63;
        int b = bb >> 1, br = bb & 1;
        const float* Bm = br ? (flip + (size_t)b * 64 * HW)
                             : (x + (size_t)b * 128 * HW + (size_t)64 * HW);
        const int* cf = (br ? cff : cfo) + (size_t)b * HW;
        const float* row = Bm + (size_t)c * HW;
        float acc = 0.f;
        for (int j = t; j < HW; j += 256) {
            if (cf[j]) acc += row[j];
        }
        for (int off = 32; off > 0; off >>= 1) acc += __shfl_down(acc, off, 64);
        __shared__ float part[4];
        int lane = t & 63, w = t >> 6;
        if (lane == 0) part[w] = acc;
        __syncthreads();
        if (t == 0) {
            float s = part[0] + part[1] + part[2] + part[3];
            if (br) Sf[b * 64 + c] = s; else So[b * 64 + c] = s;
        }
    }
    grid_barrier(&bar[1], EPI_BLOCKS);

    // ---- Phase 3: assemble [4][192][9216] ----
    const int TOT4 = 4 * 192 * (HW / 4);           // 1,769,472 float4
    const int PER_B4 = 192 * (HW / 4);
    for (int idx = g; idx < TOT4; idx += EPI_BLOCKS * 256) {
        int b = idx / PER_B4;
        int rem = idx - b * PER_B4;
        int ch = rem / (HW / 4);
        int p4 = rem % (HW / 4);
        float4 v;
        if (ch < 128) {
            v = reinterpret_cast<const float4*>(x + ((size_t)b * 128 + ch) * HW)[p4];
        } else {
            int c = ch - 128;
            int pix = p4 * 4;
            int r = pix / 96, cc = pix % 96;
            float so = So[b * 64 + c], sf = Sf[b * 64 + c];
            float vals[4];
            #pragma unroll
            for (int i = 0; i < 4; ++i) {
                int ccc = cc + i;
                if (r >= 24 && r < 72 && ccc >= 20 && ccc < 68) {
                    int mm = (r - 24) * 48 + (ccc - 20);
                    vals[i] = ori[b * MROWS + mm] ? so : sf;
                } else vals[i] = 0.f;
            }
            v = make_float4(vals[0], vals[1], vals[2], vals[3]);
        }
        reinterpret_cast<float4*>(out)[idx] = v;
    }
}

extern "C" void kernel_launch(void* const* d_in, const int* in_sizes, int n_in,
                              void* d_out, int out_size, void* d_ws, size_t ws_size,
                              hipStream_t stream) {
    const float* x    = (const float*)d_in[0];   // [4,128,9216]
    const float* flip = (const float*)d_in[1];   // [4,64,9216]
    char* w = (char*)d_ws;
    half8* bpB  = (half8*)(w + OFF_BPB);
    half8* apA  = (half8*)(w + OFF_APA);
    float* pval = (float*)(w + OFF_PVAL);
    int*   pidx = (int*)  (w + OFF_PIDX);
    int*   ori  = (int*)  (w + OFF_ORI);
    int*   cfo  = (int*)  (w + OFF_CFO);
    int*   cff  = (int*)  (w + OFF_CFF);
    float* So   = (float*)(w + OFF_SO);
    float* Sf   = (float*)(w + OFF_SF);
    float* invA = (float*)(w + OFF_INVA);
    int*   bar  = (int*)  (w + OFF_BAR);
    float* out  = (float*)d_out;

    pack_kernel<<<dim3(324, 8), 256, 0, stream>>>(x, flip, bpB, apA, invA, cfo, cff, bar);
    argmax_kernel<<<dim3(144, 18), 128, 0, stream>>>(apA, bpB, pval, pidx);
    epilogue_kernel<<<EPI_BLOCKS, 256, 0, stream>>>(x, flip, pval, pidx, invA, ori,
                                                    cfo, cff, So, Sf, out, bar);
}

// Round 11
// 236.007 us; speedup vs baseline: 1.5632x; 1.5632x over previous
//
#include <hip/hip_runtime.h>
#include <cfloat>
#include <cstddef>
#include <cstdint>

#define HW 9216
#define MROWS 2304
#define STRIPS 18
#define GPS 32          // 16-col groups per strip (STRIPW 512)
#define NGRP 576        // 9216/16 total groups

typedef _Float16 half8 __attribute__((ext_vector_type(8)));
typedef float f32x4 __attribute__((ext_vector_type(4)));

// bpack (B fragments, 16x16x32 layout): half8 index = (((dt*8+bb)*2 + c)*576 + g)*64 + lane
// apack (A fragments): half8 index = ((((bb*36+rg)*4 + rt)*2 + c)*2 + dt)*64 + lane
constexpr size_t OFF_BPB  = 0;                         // 18,874,368 B
constexpr size_t OFF_APA  = OFF_BPB + 2ull*8*2*NGRP*64*16;
constexpr size_t OFF_PVAL = OFF_APA + 8ull*36*4*2*2*64*16;     // +4,718,592
constexpr size_t OFF_PIDX = OFF_PVAL + 8ull*STRIPS*MROWS*4;    // 1,327,104 each
constexpr size_t OFF_ORI  = OFF_PIDX + 8ull*STRIPS*MROWS*4;
constexpr size_t OFF_SO   = OFF_ORI  + 36864;
constexpr size_t OFF_SF   = OFF_SO   + 1024;
constexpr size_t OFF_INVA = OFF_SF   + 1024;                   // 8*2304 f32

// K0: fused pack. grid (324, 8 bb), 256t.
//  x < 288: B-side pack.  x >= 288: A-side pack + per-row inverse norms.
__global__ __launch_bounds__(256) void pack_kernel(
    const float* __restrict__ x, const float* __restrict__ flip,
    half8* __restrict__ bpB, half8* __restrict__ apA, float* __restrict__ invA)
{
    __shared__ float nsq[8][32];
    __shared__ float ivs[32];
    __shared__ float red[4][64];

    int bb = blockIdx.y, b = bb >> 1, br = bb & 1;
    int t = threadIdx.x;

    if (blockIdx.x < 288) {
        // ---- B-side ----
        int col = t & 31, oct = t >> 5;
        int j = blockIdx.x * 32 + col;
        const float* Bm = br ? (flip + (size_t)b * 64 * HW)
                             : (x + (size_t)b * 128 * HW + (size_t)64 * HW);
        float v[8];
        float part = 0.f;
        #pragma unroll
        for (int e = 0; e < 8; ++e) {
            v[e] = Bm[(size_t)(oct * 8 + e) * HW + j];
            part += v[e] * v[e];
        }
        nsq[oct][col] = part;
        __syncthreads();
        if (oct == 0) {
            float tot = 0.f;
            #pragma unroll
            for (int o = 0; o < 8; ++o) tot += nsq[o][col];
            int r = j / 96, cc = j % 96;
            int cb = br ? 28 : 20;
            bool masked = (r >= 24 && r < 72 && cc >= cb && cc < cb + 48);
            float iv = 1.f / sqrtf(tot);
            ivs[col] = masked ? __builtin_nanf("") : iv;
        }
        __syncthreads();
        float iv = ivs[col];
        half8 hv, lv;
        #pragma unroll
        for (int e = 0; e < 8; ++e) {
            float s = v[e] * iv;
            _Float16 h = (_Float16)s;
            hv[e] = h;
            lv[e] = (_Float16)(s - (float)h);
        }
        int g = j >> 4, n = j & 15, c = oct >> 2, q = oct & 3;
        int lane = n + 16 * q;
        bpB[(((size_t)(0 * 8 + bb) * 2 + c) * NGRP + g) * 64 + lane] = hv;
        bpB[(((size_t)(1 * 8 + bb) * 2 + c) * NGRP + g) * 64 + lane] = lv;
    } else {
        // ---- A-side ----
        int rg = blockIdx.x - 288;
        int ml = t & 63, s = t >> 6;
        int cbase = br ? 28 : 20;
        int m = rg * 64 + ml;
        int pix = (24 + m / 48) * 96 + cbase + (m % 48);
        const float* A = x + (size_t)b * 128 * HW;
        float v[16];
        float part = 0.f;
        #pragma unroll
        for (int e = 0; e < 16; ++e) {
            v[e] = A[(size_t)(s * 16 + e) * HW + pix];
            part += v[e] * v[e];
        }
        red[s][ml] = part;
        __syncthreads();
        if (s == 0) {
            float tot = red[0][ml] + red[1][ml] + red[2][ml] + red[3][ml];
            invA[bb * MROWS + m] = 1.f / sqrtf(tot);
        }
        int rt = ml >> 4;
        size_t fragbase = (((size_t)bb * 36 + rg) * 4 + rt) * 2;
        #pragma unroll
        for (int h = 0; h < 2; ++h) {
            int o = 2 * s + h;
            int c = o >> 2, q = o & 3;
            int lane = (ml & 15) + 16 * q;
            half8 hv, lv;
            #pragma unroll
            for (int e = 0; e < 8; ++e) {
                float a = v[h * 8 + e];
                _Float16 hh = (_Float16)a;
                hv[e] = hh;
                lv[e] = (_Float16)(a - (float)hh);
            }
            apA[((fragbase + c) * 2 + 0) * 64 + lane] = hv;
            apA[((fragbase + c) * 2 + 1) * 64 + lane] = lv;
        }
    }
}

// K1: MFMA masked-argmax, fp16 split-3, 16x16x32_f16. 128t blocks (2 waves),
// wave = one (bb,strip,rg) unit; no LDS, no barriers; double-buffered B prefetch.
// NOTE: reg cap must stay >= ~144 (unified VGPR+AGPR) -> max 3 waves/EU, else spill (R9).
// grid: x = 144 (bb + 8*strip -> XCD pinning on bb), y = 18 (rg pairs).
__global__ __launch_bounds__(128, 3) void argmax_kernel(
    const half8* __restrict__ apA, const half8* __restrict__ bpB,
    float* __restrict__ pval, int* __restrict__ pidx)
{
    int bb = blockIdx.x & 7, strip = blockIdx.x >> 3;
    int wv = threadIdx.x >> 6, lane = threadIdx.x & 63;
    int rg = blockIdx.y * 2 + wv;
    int n = lane & 15;

    half8 ah[4][2], al[4][2];
    {
        size_t base = ((size_t)bb * 36 + rg) * 4;
        #pragma unroll
        for (int rt = 0; rt < 4; ++rt)
            #pragma unroll
            for (int c = 0; c < 2; ++c) {
                ah[rt][c] = apA[(((base + rt) * 2 + c) * 2 + 0) * 64 + lane];
                al[rt][c] = apA[(((base + rt) * 2 + c) * 2 + 1) * 64 + lane];
            }
    }

    float rv[16]; int rix[16];
    #pragma unroll
    for (int r = 0; r < 16; ++r) { rv[r] = -FLT_MAX; rix[r] = 0x7fffffff; }

    const f32x4 ZERO = {};
    int g0 = strip * GPS;

    const half8* pH0 = bpB + (((size_t)(bb) * 2 + 0) * NGRP) * 64 + lane;
    const half8* pH1 = bpB + (((size_t)(bb) * 2 + 1) * NGRP) * 64 + lane;
    const half8* pL0 = bpB + (((size_t)(8 + bb) * 2 + 0) * NGRP) * 64 + lane;
    const half8* pL1 = bpB + (((size_t)(8 + bb) * 2 + 1) * NGRP) * 64 + lane;

    half8 buf0[4], buf1[4];
    auto ldb = [&](half8* d, int g) {
        d[0] = pH0[(size_t)g * 64];
        d[1] = pH1[(size_t)g * 64];
        d[2] = pL0[(size_t)g * 64];
        d[3] = pL1[(size_t)g * 64];
    };
    auto compute = [&](const half8* bf, int gi) {
        f32x4 acc[4];
        #pragma unroll
        for (int rt = 0; rt < 4; ++rt) {
            acc[rt] = __builtin_amdgcn_mfma_f32_16x16x32_f16(ah[rt][0], bf[0], ZERO, 0, 0, 0);
            acc[rt] = __builtin_amdgcn_mfma_f32_16x16x32_f16(al[rt][0], bf[0], acc[rt], 0, 0, 0);
            acc[rt] = __builtin_amdgcn_mfma_f32_16x16x32_f16(ah[rt][0], bf[2], acc[rt], 0, 0, 0);
            acc[rt] = __builtin_amdgcn_mfma_f32_16x16x32_f16(ah[rt][1], bf[1], acc[rt], 0, 0, 0);
            acc[rt] = __builtin_amdgcn_mfma_f32_16x16x32_f16(al[rt][1], bf[1], acc[rt], 0, 0, 0);
            acc[rt] = __builtin_amdgcn_mfma_f32_16x16x32_f16(ah[rt][1], bf[3], acc[rt], 0, 0, 0);
        }
        int j = (g0 + gi) * 16 + n;
        #pragma unroll
        for (int rt = 0; rt < 4; ++rt)
            #pragma unroll
            for (int r = 0; r < 4; ++r) {
                float s = acc[rt][r];
                int slot = rt * 4 + r;
                if (s > rv[slot]) { rv[slot] = s; rix[slot] = j; }
            }
    };

    ldb(buf0, g0);
    #pragma unroll 1
    for (int gi = 0; gi < GPS; gi += 2) {
        ldb(buf1, g0 + gi + 1);
        compute(buf0, gi);
        int gnext = gi + 2 < GPS ? g0 + gi + 2 : g0 + gi + 1;  // clamp (dummy reload)
        ldb(buf0, gnext);
        compute(buf1, gi + 1);
    }

    #pragma unroll
    for (int slot = 0; slot < 16; ++slot) {
        float v = rv[slot]; int ix = rix[slot];
        #pragma unroll
        for (int off = 1; off <= 8; off <<= 1) {
            float ov = __shfl_xor(v, off, 16);
            int   oi = __shfl_xor(ix, off, 16);
            if (ov > v || (ov == v && oi < ix)) { v = ov; ix = oi; }
        }
        if (n == 0) {
            int q = lane >> 4;
            int rt = slot >> 2, r = slot & 3;
            int mm = rg * 64 + rt * 16 + q * 4 + r;
            pval[((size_t)bb * STRIPS + strip) * MROWS + mm] = v;
            pidx[((size_t)bb * STRIPS + strip) * MROWS + mm] = ix;
        }
    }
}

// K2: fused merge+ssum. grid 512 = (bb<<6)|c, 256t. Each block redoes the strip-merge
// for its bb (pval/pidx are L2-resident), dedups best columns into an LDS bitmap,
// then sums its channel's flagged columns. (br==0,c==0) blocks also write ori.
__global__ __launch_bounds__(256) void mergesum_kernel(
    const float* __restrict__ x, const float* __restrict__ flip,
    const float* __restrict__ pval, const int* __restrict__ pidx,
    const float* __restrict__ invA, int* __restrict__ ori,
    float* __restrict__ So, float* __restrict__ Sf)
{
    int pair = blockIdx.x;
    int bb = pair >> 6, c = pair & 63;
    int b = bb >> 1, br = bb & 1;
    int t = threadIdx.x;

    __shared__ uint32_t bitmap[288];   // 9216 bits
    for (int i = t; i < 288; i += 256) bitmap[i] = 0;
    __syncthreads();

    bool do_ori = (br == 0) && (c == 0);
    for (int m = t; m < MROWS; m += 256) {       // 9 iters
        float v = -FLT_MAX; int id = 0x7fffffff;
        #pragma unroll
        for (int s = 0; s < STRIPS; ++s) {
            float pv = pval[((size_t)bb * STRIPS + s) * MROWS + m];
            int   pi = pidx[((size_t)bb * STRIPS + s) * MROWS + m];
            if (pv > v || (pv == v && pi < id)) { v = pv; id = pi; }
        }
        atomicOr(&bitmap[id >> 5], 1u << (id & 31));
        if (do_ori) {
            int obb = bb + 1;
            float v2 = -FLT_MAX; int id2 = 0x7fffffff;
            #pragma unroll
            for (int s = 0; s < STRIPS; ++s) {
                float pv = pval[((size_t)obb * STRIPS + s) * MROWS + m];
                int   pi = pidx[((size_t)obb * STRIPS + s) * MROWS + m];
                if (pv > v2 || (pv == v2 && pi < id2)) { v2 = pv; id2 = pi; }
            }
            float bv0 = v  * invA[bb  * MROWS + m];
            float bv1 = v2 * invA[obb * MROWS + m];
            ori[b * MROWS + m] = (bv0 >= bv1) ? 1 : 0;
        }
    }
    __syncthreads();

    const float* Bm = br ? (flip + (size_t)b * 64 * HW)
                         : (x + (size_t)b * 128 * HW + (size_t)64 * HW);
    const float* row = Bm + (size_t)c * HW;
    float acc = 0.f;
    for (int w = t; w < 288; w += 256) {
        uint32_t bits = bitmap[w];
        int base = w * 32;
        while (bits) {
            int bit = __ffs(bits) - 1;
            bits &= bits - 1;
            acc += row[base + bit];
        }
    }
    for (int off = 32; off > 0; off >>= 1) acc += __shfl_down(acc, off, 64);
    __shared__ float part[4];
    int lane = t & 63, w4 = t >> 6;
    if (lane == 0) part[w4] = acc;
    __syncthreads();
    if (t == 0) {
        float s = part[0] + part[1] + part[2] + part[3];
        if (br) Sf[b * 64 + c] = s; else So[b * 64 + c] = s;
    }
}

// K3: assemble output [4][192][9216]
__global__ __launch_bounds__(256) void assemble_kernel(
    const float* __restrict__ x, const int* __restrict__ ori,
    const float* __restrict__ So, const float* __restrict__ Sf,
    float* __restrict__ out)
{
    int idx = blockIdx.x * 256 + threadIdx.x;      // float4 index; grid covers exactly
    const int PER_B4 = 192 * (HW / 4);             // 442368
    int b = idx / PER_B4;
    int rem = idx - b * PER_B4;
    int ch = rem / (HW / 4);
    int p4 = rem % (HW / 4);
    float4 v;
    if (ch < 128) {
        v = reinterpret_cast<const float4*>(x + ((size_t)b * 128 + ch) * HW)[p4];
    } else {
        int c = ch - 128;
        int pix = p4 * 4;
        int r = pix / 96, cc = pix % 96;           // 4 consecutive pixels share the row
        float so = So[b * 64 + c], sf = Sf[b * 64 + c];
        float vals[4];
        #pragma unroll
        for (int i = 0; i < 4; ++i) {
            int ccc = cc + i;
            if (r >= 24 && r < 72 && ccc >= 20 && ccc < 68) {
                int mm = (r - 24) * 48 + (ccc - 20);
                vals[i] = ori[b * MROWS + mm] ? so : sf;
            } else vals[i] = 0.f;
        }
        v = make_float4(vals[0], vals[1], vals[2], vals[3]);
    }
    reinterpret_cast<float4*>(out)[idx] = v;
}

extern "C" void kernel_launch(void* const* d_in, const int* in_sizes, int n_in,
                              void* d_out, int out_size, void* d_ws, size_t ws_size,
                              hipStream_t stream) {
    const float* x    = (const float*)d_in[0];   // [4,128,9216]
    const float* flip = (const float*)d_in[1];   // [4,64,9216]
    char* w = (char*)d_ws;
    half8* bpB  = (half8*)(w + OFF_BPB);
    half8* apA  = (half8*)(w + OFF_APA);
    float* pval = (float*)(w + OFF_PVAL);
    int*   pidx = (int*)  (w + OFF_PIDX);
    int*   ori  = (int*)  (w + OFF_ORI);
    float* So   = (float*)(w + OFF_SO);
    float* Sf   = (float*)(w + OFF_SF);
    float* invA = (float*)(w + OFF_INVA);
    float* out  = (float*)d_out;

    pack_kernel<<<dim3(324, 8), 256, 0, stream>>>(x, flip, bpB, apA, invA);
    argmax_kernel<<<dim3(144, 18), 128, 0, stream>>>(apA, bpB, pval, pidx);
    mergesum_kernel<<<512, 256, 0, stream>>>(x, flip, pval, pidx, invA, ori, So, Sf);
    assemble_kernel<<<6912, 256, 0, stream>>>(x, ori, So, Sf, out);
}